// Round 6
// baseline (727.796 us; speedup 1.0000x reference)
//
#include <hip/hip_runtime.h>

// Problem dims (fixed by reference setup_inputs)
#define BB   2
#define CF_  64
#define CC   3
#define HH   64
#define WW   2048
#define HWs  (HH * WW)      // 131072
#define KK   9
#define TPB  512            // one block = one (b, cf, h) output row; thread = 4 px

typedef float f4 __attribute__((ext_vector_type(4)));

// out[b, cf*9+n, h, w] = feat[b,cf,h+di,w+dj] * relu(M[cf,:]·rel[:,n])
// M = w1 @ w0;  rel[c,n] = (center_c==-1) ? 0 : sample_c,n - center_c
// Identity: M·rel = Σc (m_c k_c)·s_c − Σc (m_c k_c)·center_c  (k_c = center_c != -1)
// OOB taps: reference zero-pads FEATURES, so zeroing the feature tap forces
// out=0 regardless of the (garbage/clamped) coord sample.
//
// THEORY-B STRUCTURE: each block writes 9 FULL 8-KB contiguous plane-rows
// (1 KB lane-contiguous per wave-store), instead of waves scattering 512-B
// islands across planes 512 KB apart. Dense sequential write streams keep
// HBM row-activate overhead amortized (fill kernel proves 6.3 TB/s this way).
__global__ __launch_bounds__(TPB, 4) void fused_unfold_mlp_kernel(
    const float* __restrict__ feat,
    const float* __restrict__ coord,
    const float* __restrict__ w0,
    const float* __restrict__ w1,
    float* __restrict__ out)
{
    const int t  = threadIdx.x;
    const int id = blockIdx.x;              // [b:1][cf:6][h:6] — h in low bits:
    const int h  = id & (HH - 1);           // consecutive blocks continue the
    const int cf = (id >> 6) & (CF_ - 1);   // same 9 plane streams in h order
    const int b  = id >> 12;

    // M row for this cf (block-uniform; scalar loads + readfirstlane hoist)
    float m[CC];
#pragma unroll
    for (int c = 0; c < CC; c++) {
        float acc = 0.f;
#pragma unroll
        for (int k = 0; k < 16; k++)
            acc = fmaf(w1[cf * 16 + k], w0[k * CC + c], acc);
        m[c] = __uint_as_float(__builtin_amdgcn_readfirstlane(__float_as_uint(acc)));
    }

    const int g  = t * 4;                       // first of this thread's 4 cols
    const int bL = (g >= 4) ? (g - 4) : 0;              // aligned left window
    const int bR = (g + 4 <= WW - 4) ? (g + 4) : (WW - 4); // aligned right window
    const bool eL = (t == 0), eR = (t == TPB - 1);

    const int r0 = (h > 0      ? h - 1 : 0     ) * WW;
    const int r1 = h * WW;
    const int r2 = (h < HH - 1 ? h + 1 : HH - 1) * WW;
    const float rm0 = (h > 0)      ? 1.f : 0.f;   // row masks (OOB row -> 0)
    const float rm2 = (h < HH - 1) ? 1.f : 0.f;

    const float* __restrict__ cb = coord + (size_t)b * CC * HWs;
    const float* __restrict__ fr = feat  + ((size_t)b * CF_ + cf) * HWs;
    float* __restrict__ ob = out + (size_t)(b * CF_ + cf) * KK * HWs
                                 + (size_t)h * WW + g;

    float mk[CC][4], bb[4];

    // window: w[0..3]=@bL, w[4..7]=@g, w[8..11]=@bR; tap col g+d -> w[4+d]
    // (clamped bases make edge taps read don't-care in-bounds values)
    auto ldwin = [&](const float* base, float* w) {
        *(f4*)(w)     = *(const f4*)(base + bL);
        *(f4*)(w + 4) = *(const f4*)(base + g);
        *(f4*)(w + 8) = *(const f4*)(base + bR);
    };

    // one kernel-row r: loads, (optional) mask build, 3 plane-row stores
    auto doRow = [&](int ro, float rm, int n0, bool isCenter) {
        float cw[CC][12], fw[12];
#pragma unroll
        for (int c = 0; c < CC; c++) ldwin(cb + (size_t)c * HWs + ro, cw[c]);
        ldwin(fr + ro, fw);

        if (isCenter) {       // centers are cols g..g+3 of the mid row
#pragma unroll
            for (int px = 0; px < 4; px++) {
                float acc = 0.f;
#pragma unroll
                for (int c = 0; c < CC; c++) {
                    const float cen = cw[c][4 + px];
                    const float kk  = (cen != -1.0f) ? 1.f : 0.f;
                    mk[c][px] = m[c] * kk;
                    acc = fmaf(mk[c][px], cen, acc);
                }
                bb[px] = acc;
            }
        }

#pragma unroll
        for (int j = 0; j < 3; j++) {           // n = n0 + j
            f4 v;
#pragma unroll
            for (int px = 0; px < 4; px++) {
                const int idx = 4 + px + j - 1; // tap col g+px+j-1
                float wgt = fmaf(mk[2][px], cw[2][idx],
                            fmaf(mk[1][px], cw[1][idx],
                            fmaf(mk[0][px], cw[0][idx], -bb[px])));
                float ft = fw[idx];
                if (px == 0 && j == 0) ft = eL ? 0.f : ft;  // col g-1 @ t=0
                if (px == 3 && j == 2) ft = eR ? 0.f : ft;  // col g+4 @ t=511
                v[px] = ft * rm * fmaxf(wgt, 0.f);
            }
            __builtin_nontemporal_store(v, (f4*)(ob + (size_t)(n0 + j) * HWs));
        }
    };

    doRow(r1, 1.f, 3, true);    // center row first (builds mk, bb)
    doRow(r0, rm0, 0, false);
    doRow(r2, rm2, 6, false);
}

extern "C" void kernel_launch(void* const* d_in, const int* in_sizes, int n_in,
                              void* d_out, int out_size, void* d_ws, size_t ws_size,
                              hipStream_t stream) {
    const float* feat  = (const float*)d_in[0];
    const float* coord = (const float*)d_in[1];
    const float* w0    = (const float*)d_in[2];
    const float* w1    = (const float*)d_in[3];
    float* out = (float*)d_out;

    const int blocks = BB * CF_ * HH;   // 8192 blocks of 512 threads
    fused_unfold_mlp_kernel<<<blocks, TPB, 0, stream>>>(feat, coord, w0, w1, out);
}